// Round 6
// baseline (414.494 us; speedup 1.0000x reference)
//
#include <hip/hip_runtime.h>
#include <hip/hip_bf16.h>
#include <hip/hip_cooperative_groups.h>
#include <stdint.h>

#define B_ 8
#define T_ 2048
#define E_ 1024
#define H_ 128
#define BT_ (B_*T_)

typedef unsigned short u16;
typedef unsigned int u32;
typedef __attribute__((ext_vector_type(4))) unsigned short u16x4;
typedef __attribute__((ext_vector_type(8))) short short8;
typedef __attribute__((ext_vector_type(4))) float f32x4;

#define MFMA_BF16(a,b,c) __builtin_amdgcn_mfma_f32_16x16x32_bf16((a),(b),(c),0,0,0)

#define SBAR() do { __builtin_amdgcn_sched_barrier(0); __builtin_amdgcn_s_barrier(); __builtin_amdgcn_sched_barrier(0); } while(0)
#define WAITL0() asm volatile("s_waitcnt lgkmcnt(0)" ::: "memory")

__device__ __forceinline__ u16 bf16u(float f) {
  union { float f; unsigned u; } v; v.f = f;
  unsigned r = v.u + 0x7FFFu + ((v.u >> 16) & 1u);
  return (u16)(r >> 16);
}
__device__ __forceinline__ float ubf16(u16 u) {
  union { unsigned u; float f; } v; v.u = ((unsigned)u) << 16; return v.f;
}

// async global->LDS, 16B per lane; lds dest must be wave-uniform base.
__device__ __forceinline__ void gl16(const void* g, void* l) {
  __builtin_amdgcn_global_load_lds(
      (const __attribute__((address_space(1))) void*)g,
      (__attribute__((address_space(3))) void*)l, 16, 0, 0);
}

// Stage an R-row tile, CB bytes per row, into LDS [R][CB] (linear dest).
// SWZ via pre-swizzled GLOBAL source; readers XOR 16B-slot with (row&7).
template<int R, int CB, bool SWZ>
__device__ __forceinline__ void stage_tile(const char* g, int gstride, char* lds) {
  const int lane = threadIdx.x & 63;
  const int wid  = threadIdx.x >> 6;
  constexpr int LPR   = CB / 16;
  constexpr int RPC   = 1024 / CB;
  constexpr int CALLS = (R * CB) / 1024;
  constexpr int CPW   = CALLS / 4;
#pragma unroll
  for (int c = 0; c < CPW; ++c) {
    const int call = wid * CPW + c;
    const int r0   = call * RPC;            // wave-uniform
    const int row  = r0 + lane / LPR;
    int s = lane % LPR;
    if (SWZ) s = s ^ (row & 7);
    gl16(g + (size_t)row * gstride + s * 16, lds + (size_t)r0 * CB);
  }
}

// Read a bf16x8 fragment from a SWZ-staged tile. colu16 multiple of 8.
__device__ __forceinline__ short8 fragr(const u16* lds, int row, int colu16, int CBu) {
  const int slot = (colu16 >> 3) ^ (row & 7);
  return *(const short8*)&lds[(size_t)row * CBu + (slot << 3)];
}

// ---------------- kernel 0: Wt build + colsum zero (tiny) ----------------
__global__ void k_prep(const float* __restrict__ Wq, const float* __restrict__ Wk,
                       const float* __restrict__ Wv, u16* __restrict__ Wt,
                       float* __restrict__ colsum) {
  const int gidx = blockIdx.x * 256 + threadIdx.x;
  if (gidx < BT_) colsum[gidx] = 0.f;
  if (gidx < 384 * 1024) {
    int r = gidx >> 10;
    int e = gidx & 1023;
    int i = r >> 7;           // 0:q 1:k 2:v
    int h = r & 127;
    const float* W = (i == 0) ? Wq : (i == 1) ? Wk : Wv;
    float v = W[(size_t)e * 128 + h];
    if (i == 0) v *= 0.03125f;   // fold 1/sqrt(E)=1/32 into Q
    Wt[gidx] = bf16u(v);
  }
}

// ---------------- kernel 1: QKV GEMM direct from X fp32 ----------------
// grid 256 (m-tiles of 64), N=384 full, BK=64. A: reg-staged fp32->bf16 with
// 2-deep prefetch; B: gl16 dbuf. LDS 112KB -> 1 wg/CU.
__global__ __launch_bounds__(256, 1) void k_qkv(const float* __restrict__ X,
    const u16* __restrict__ Wt, u16* __restrict__ Qs, u16* __restrict__ Kb,
    u16* __restrict__ Vt) {
  __shared__ __align__(16) u16 As[2][64 * 64];    // 16KB
  __shared__ __align__(16) u16 Bs[2][384 * 64];   // 96KB
  const int m0 = blockIdx.x * 64;
  const int tid = threadIdx.x;
  const int lane = tid & 63, wid = tid >> 6;
  const int ln = lane & 15, h4 = lane >> 4;
  const int wr = (wid >> 1) * 32, wc = (wid & 1) * 192;
  const int ar_r = tid >> 2, ar_c = tid & 3;      // A-stage: row, 16-float group
  const float* xrow = X + (size_t)(m0 + ar_r) * E_ + ar_c * 16;
  f32x4 acc[2][12] = {};
  float4 arA[4], arB[4];

  auto issueA = [&](int t, float4* ar) {
    const float4* src = (const float4*)(xrow + t * 64);
#pragma unroll
    for (int j = 0; j < 4; ++j) ar[j] = src[j];
  };
  auto writeA = [&](int buf, const float4* ar) {
    u16 tmp[16];
#pragma unroll
    for (int j = 0; j < 4; ++j) {
      tmp[4*j+0] = bf16u(ar[j].x); tmp[4*j+1] = bf16u(ar[j].y);
      tmp[4*j+2] = bf16u(ar[j].z); tmp[4*j+3] = bf16u(ar[j].w);
    }
    const int s0 = ar_c * 2;
    u16* base = As[buf] + ar_r * 64;
    *(short8*)(base + (((s0    ) ^ (ar_r & 7)) << 3)) = *(const short8*)&tmp[0];
    *(short8*)(base + (((s0 + 1) ^ (ar_r & 7)) << 3)) = *(const short8*)&tmp[8];
  };
  auto stageB = [&](int t, int buf) {
    stage_tile<384, 128, true>((const char*)(Wt + t * 64), 2048, (char*)Bs[buf]);
  };
  auto compute = [&](int c) {
#pragma unroll
    for (int kk = 0; kk < 2; ++kk) {
      short8 a[2], b[12];
#pragma unroll
      for (int mf = 0; mf < 2; ++mf)
        a[mf] = fragr(As[c], wr + mf * 16 + ln, kk * 32 + h4 * 8, 64);
#pragma unroll
      for (int nf = 0; nf < 12; ++nf)
        b[nf] = fragr(Bs[c], wc + nf * 16 + ln, kk * 32 + h4 * 8, 64);
#pragma unroll
      for (int mf = 0; mf < 2; ++mf)
#pragma unroll
        for (int nf = 0; nf < 12; ++nf)
          acc[mf][nf] = MFMA_BF16(a[mf], b[nf], acc[mf][nf]);
    }
  };

  // prologue: A(0), B(0), A(1) in flight; A(0) -> LDS
  issueA(0, arA);
  stageB(0, 0);
  issueA(1, arB);
  writeA(0, arA);                                       // waits A(0) only
  asm volatile("s_waitcnt vmcnt(4)" ::: "memory");      // B(0) done; A(1) out
  WAITL0(); SBAR();

  auto body = [&](int t, float4* issDst, const float4* cvtSrc) {
    const int c = t & 1;
    if (t < 15) stageB(t + 1, c ^ 1);
    if (t < 14) issueA(t + 2, issDst);
    compute(c);
    if (t < 15) {
      writeA(c ^ 1, cvtSrc);                            // A(t+1); auto-waited
      if (t < 14) asm volatile("s_waitcnt vmcnt(4)" ::: "memory");
      else        asm volatile("s_waitcnt vmcnt(0)" ::: "memory");
      WAITL0(); SBAR();
    }
  };
  for (int tt = 0; tt < 16; tt += 2) {
    body(tt,     arA, arB);
    body(tt + 1, arB, arA);
  }

#pragma unroll
  for (int mf = 0; mf < 2; ++mf)
#pragma unroll
    for (int nf = 0; nf < 12; ++nf) {
      const int cg = wc + nf * 16 + ln;
#pragma unroll
      for (int i = 0; i < 4; ++i) {
        const int r = m0 + wr + mf * 16 + h4 * 4 + i;
        const u16 u = bf16u(acc[mf][nf][i]);
        if (cg < 128)      Qs[(size_t)r * H_ + cg] = u;
        else if (cg < 256) Kb[(size_t)r * H_ + (cg - 128)] = u;
        else {
          const int bb = r >> 11, t2 = r & (T_ - 1);
          Vt[((size_t)bb * H_ + (cg - 256)) * T_ + t2] = u;  // V transposed
        }
      }
    }
}

// ================= fused phases (device functions) =================

// Phase S: score. wg -> (c,a,b); 2-3 causal tiles; S=QK^T, exp+mask,
// colsum atomics, P stored linear to global.
__device__ void phase_score(int wg, u16* lds, const u16* Qs, const u16* Kb,
                            u16* P, float* colsum) {
  u16* Kf = lds;   // 32KB
  const int c = wg >> 6, a = (wg >> 3) & 7, b = wg & 7;
  const int lo = (c * 17) >> 3, hi = ((c + 1) * 17) >> 3;
  const int lane = threadIdx.x & 63, wid = threadIdx.x >> 6;
  const int ln = lane & 15, h4 = lane >> 4;
  const int wq0 = wid * 32;
  const bool evenlane = !(ln & 1);
  int curqt = -1;
  short8 qa[2][4];
  for (int t = lo; t < hi; ++t) {
    const int qt = (t <= a) ? a : 15 - a;
    const int kt = (t <= a) ? t : t - (a + 1);
    stage_tile<128, 256, true>((const char*)(Kb + ((size_t)b * T_ + kt * 128) * H_), H_ * 2, (char*)Kf);
    if (qt != curqt) {
#pragma unroll
      for (int mf = 0; mf < 2; ++mf)
#pragma unroll
        for (int kk = 0; kk < 4; ++kk)
          qa[mf][kk] = *(const short8*)&Qs[((size_t)b * T_ + qt * 128 + wq0 + mf * 16 + ln) * H_ + kk * 32 + h4 * 8];
      curqt = qt;
    }
    asm volatile("s_waitcnt vmcnt(0)" ::: "memory");
    SBAR();

    f32x4 acc[2][8] = {};
#pragma unroll
    for (int kk = 0; kk < 4; ++kk) {
#pragma unroll
      for (int nf = 0; nf < 8; ++nf) {
        short8 bv = fragr(Kf, nf * 16 + ln, kk * 32 + h4 * 8, 128);
#pragma unroll
        for (int mf = 0; mf < 2; ++mf)
          acc[mf][nf] = MFMA_BF16(qa[mf][kk], bv, acc[mf][nf]);
      }
    }

    const bool diag = (qt == kt);
#pragma unroll
    for (int nf = 0; nf < 8; ++nf) {
      float s = 0.f;
      const int k = nf * 16 + ln;
#pragma unroll
      for (int mf = 0; mf < 2; ++mf) {
#pragma unroll
        for (int i = 0; i < 4; ++i) {
          const int q = wq0 + mf * 16 + h4 * 4 + i;
          float w = __expf(acc[mf][nf][i]);
          if (diag && q < k) w = 0.f;
          acc[mf][nf][i] = w;
          s += w;
        }
      }
      s += __shfl_xor(s, 16);
      s += __shfl_xor(s, 32);
      if (h4 == 0) atomicAdd(&colsum[(size_t)b * T_ + kt * 128 + nf * 16 + ln], s);
    }

    u16* ptile = P + (((size_t)b * 136 + (size_t)qt * (qt + 1) / 2 + kt) << 14);
#pragma unroll
    for (int mf = 0; mf < 2; ++mf)
#pragma unroll
      for (int nf = 0; nf < 8; ++nf) {
        f32x4 v = acc[mf][nf];
        f32x4 pv_;
#pragma unroll
        for (int i = 0; i < 4; ++i) pv_[i] = __shfl_xor(v[i], 1);
#pragma unroll
        for (int j = 0; j < 2; ++j) {
          const int i = evenlane ? j : (2 + j);
          const float flo = evenlane ? v[i] : pv_[i];
          const float fhh = evenlane ? pv_[i] : v[i];
          const u32 pk = (u32)bf16u(flo) | ((u32)bf16u(fhh) << 16);
          const int row = wq0 + mf * 16 + h4 * 4 + i;
          const int kc  = nf * 16 + (ln & ~1);
          *(u32*)((char*)ptile + row * 256 + kc * 2) = pk;
        }
      }
    WAITL0();   // Kf ds_reads retired; P stores remain in flight
    SBAR();
  }
}

// Phase F: V' = V * (1/colsum), grid-stride over 512 wgs.
__device__ void phase_finalize(int wg, const float* colsum, u16* Vt) {
  for (int i8 = wg * 256 + threadIdx.x; i8 < BT_ * H_ / 8; i8 += 512 * 256) {
    const int b  = i8 >> 15;
    const int r  = i8 & 32767;
    const int h  = r >> 8;
    const int t8 = r & 255;
    u16* p = Vt + ((size_t)b * H_ + h) * T_ + t8 * 8;
    const float* csp = colsum + (size_t)b * T_ + t8 * 8;
    short8 v = *(short8*)p;
    short8 o;
#pragma unroll
    for (int j = 0; j < 8; ++j) {
      float f = ubf16((u16)v[j]) / csp[j];
      o[j] = (short)bf16u(f);
    }
    *(short8*)p = o;
  }
}

// Phase P: O = P @ V'. wg -> (hq,b,a); snake pair, dbuf, counted vmcnt.
__device__ void phase_pv(int wg, u16* lds, const u16* P, const u16* Vt,
                         float* out) {
  u16* Pt0 = lds;              // 32KB
  u16* Pt1 = lds + 16384;      // 32KB
  u16* Vs0 = lds + 32768;      // 4KB
  u16* Vs1 = lds + 34816;      // 4KB
  const int hq = wg >> 6, b = (wg >> 3) & 7, a = wg & 7;
  const int lane = threadIdx.x & 63, wid = threadIdx.x >> 6;
  const int ln = lane & 15, h4 = lane >> 4;
  const int wq0 = wid * 32;

  auto stage = [&](int t, int buf) {
    const int qt = (t <= a) ? a : 15 - a;
    const int kt = (t <= a) ? t : t - (a + 1);
    const u16* ptile = P + (((size_t)b * 136 + (size_t)qt * (qt + 1) / 2 + kt) << 14);
    stage_tile<128, 256, true>((const char*)ptile, 256, (char*)(buf ? Pt1 : Pt0));
    stage_tile<16, 256, true>((const char*)(Vt + ((size_t)b * H_ + hq * 16) * T_ + kt * 128), T_ * 2, (char*)(buf ? Vs1 : Vs0));
  };

  stage(0, 0);
  f32x4 acc[2] = {};
  for (int t = 0; t < 17; ++t) {
    const int cur = t & 1;
    if (t < 16) stage(t + 1, cur ^ 1);
    if (t < 16) asm volatile("s_waitcnt vmcnt(9)" ::: "memory");
    else        asm volatile("s_waitcnt vmcnt(0)" ::: "memory");
    SBAR();
    const u16* Ptc = cur ? Pt1 : Pt0;
    const u16* Vsc = cur ? Vs1 : Vs0;
#pragma unroll
    for (int kk = 0; kk < 4; ++kk) {
      short8 bv = fragr(Vsc, ln, kk * 32 + h4 * 8, 128);
#pragma unroll
      for (int mf = 0; mf < 2; ++mf) {
        short8 av = fragr(Ptc, wq0 + mf * 16 + ln, kk * 32 + h4 * 8, 128);
        acc[mf] = MFMA_BF16(av, bv, acc[mf]);
      }
    }
    if (t == a || t == 16) {
      const int qt = (t == a) ? a : 15 - a;
#pragma unroll
      for (int mf = 0; mf < 2; ++mf) {
#pragma unroll
        for (int i = 0; i < 4; ++i) {
          const int q = qt * 128 + wq0 + mf * 16 + h4 * 4 + i;
          out[((size_t)b * T_ + q) * H_ + hq * 16 + ln] = acc[mf][i];
        }
        acc[mf] = (f32x4){0.f, 0.f, 0.f, 0.f};
      }
    }
    WAITL0();
    SBAR();
  }
}

// ---------------- fused cooperative kernel ----------------
__global__ __launch_bounds__(256, 2) void k_fused(const u16* Qs, const u16* Kb,
    u16* P, float* colsum, u16* Vt, float* out) {
  __shared__ __align__(16) u16 lds[36864];   // 72KB
  cooperative_groups::grid_group grid = cooperative_groups::this_grid();
  const int wg = blockIdx.x;
  phase_score(wg, lds, Qs, Kb, P, colsum);
  asm volatile("s_waitcnt vmcnt(0) lgkmcnt(0)" ::: "memory");
  __threadfence();
  grid.sync();
  phase_finalize(wg, colsum, Vt);
  asm volatile("s_waitcnt vmcnt(0) lgkmcnt(0)" ::: "memory");
  __threadfence();
  grid.sync();
  phase_pv(wg, lds, P, Vt, out);
}

// ---------------- standalone fallbacks (if cooperative launch fails) --------
__global__ __launch_bounds__(256, 2) void k_score_only(const u16* Qs, const u16* Kb,
    u16* P, float* colsum) {
  __shared__ __align__(16) u16 lds[16384];
  phase_score(blockIdx.x, lds, Qs, Kb, P, colsum);
}
__global__ void k_finalize_only(const float* colsum, u16* Vt) {
  phase_finalize(blockIdx.x, colsum, Vt);
}
__global__ __launch_bounds__(256, 2) void k_pv_only(const u16* P, const u16* Vt,
    float* out) {
  __shared__ __align__(16) u16 lds[36864];
  phase_pv(blockIdx.x, lds, P, Vt, out);
}

extern "C" void kernel_launch(void* const* d_in, const int* in_sizes, int n_in,
                              void* d_out, int out_size, void* d_ws, size_t ws_size,
                              hipStream_t stream) {
  const float* X  = (const float*)d_in[0];
  const float* Wq = (const float*)d_in[1];
  const float* Wk = (const float*)d_in[2];
  const float* Wv = (const float*)d_in[3];
  float* out = (float*)d_out;
  char* ws = (char*)d_ws;

  u16*   Wt     = (u16*)(ws + 0);            //    786,432
  u16*   Qs     = (u16*)(ws + 786432);       //  4,194,304
  u16*   Kb     = (u16*)(ws + 4980736);      //  4,194,304
  u16*   Vt     = (u16*)(ws + 9175040);      //  4,194,304
  float* colsum = (float*)(ws + 13369344);   //     65,536
  u16*   Pb     = (u16*)(ws + 13434880);     // 35,651,584 -> end 49,086,464

  k_prep<<<1536, 256, 0, stream>>>(Wq, Wk, Wv, Wt, colsum);
  k_qkv<<<256, 256, 0, stream>>>(X, Wt, Qs, Kb, Vt);

  void* args[6] = { (void*)&Qs, (void*)&Kb, (void*)&Pb, (void*)&colsum,
                    (void*)&Vt, (void*)&out };
  hipError_t e = hipLaunchCooperativeKernel((const void*)k_fused, dim3(512),
                                            dim3(256), args, 0, stream);
  if (e != hipSuccess) {
    k_score_only<<<512, 256, 0, stream>>>(Qs, Kb, Pb, colsum);
    k_finalize_only<<<512, 256, 0, stream>>>(colsum, Vt);
    k_pv_only<<<512, 256, 0, stream>>>(Pb, Vt, out);
  }
}